// Round 12
// baseline (1589.212 us; speedup 1.0000x reference)
//
#include <hip/hip_runtime.h>

typedef _Float16 half_t;
typedef _Float16 half8 __attribute__((ext_vector_type(8)));
typedef float f32x4 __attribute__((ext_vector_type(4)));
typedef unsigned long long u64;
typedef unsigned int u32;

#define GROUPS 16
#define WPG 8
#define NWG 128
#define THREADS 512
#define TSTEPS 512

// ws layout
#define W0_HALVES (8*8*10*64*8)    // 327680 halves
#define W1_HALVES (8*8*16*64*8)    // 524288 halves
#define X_HALVES  (512*16*1024)    // 8388608 halves
#define HX_U32    (2*GROUPS*4096)  // per layer: 2 slots x 16 groups x 4096 stamped u32

// LDS layout (dynamic): W1lds 98304 B | hbuf 2x16384 B  => 131072 B total
#define W1LDS_BYTES 98304
#define LDS_TOTAL   131072

__device__ __forceinline__ float sigm(float x){ return 1.f/(1.f+__expf(-x)); }
__device__ __forceinline__ float tanh_fast(float x){ float e=__expf(2.f*x); return 1.f - 2.f/(e+1.f); }

// W0 blocks: [jw 0..63][kc 0..9][lane][8]; wave jw owns h [jw*4, jw*4+4)
// tile row tr=lane&15: gate=tr&3, h_local=tr>>2 ; grow = gate*256 + jw*4 + h_local
// k = kc*32 + (lane>>4)*8 + jj ; K = [x(64) | h0(256)]
__global__ void prep_w0(const float* __restrict__ Wih, const float* __restrict__ Whh,
                        half_t* __restrict__ dst){
  int idx = blockIdx.x*blockDim.x + threadIdx.x;
  if (idx >= 8*8*10*64) return;
  int lane = idx & 63;
  int kc = (idx >> 6) % 10;
  int jw = idx / 640;
  int tr = lane & 15, kg = lane >> 4;
  int grow = (tr&3)*256 + jw*4 + (tr>>2);
  int k0 = kc*32 + kg*8;
  half_t* d = dst + (size_t)idx*8;
#pragma unroll
  for (int jj=0;jj<8;jj++){
    int k = k0 + jj;
    float v = (k < 64) ? Wih[grow*64 + k] : Whh[grow*256 + (k - 64)];
    d[jj] = (half_t)v;
  }
}

// W1 blocks: [jw][kc 0..15][lane][8]; K = [h0(256) | h1(256)]
__global__ void prep_w1(const float* __restrict__ Wih, const float* __restrict__ Whh,
                        half_t* __restrict__ dst){
  int idx = blockIdx.x*blockDim.x + threadIdx.x;
  if (idx >= 8*8*16*64) return;
  int lane = idx & 63;
  int kc = (idx >> 6) & 15;
  int jw = idx >> 10;
  int tr = lane & 15, kg = lane >> 4;
  int grow = (tr&3)*256 + jw*4 + (tr>>2);
  int k0 = kc*32 + kg*8;
  half_t* d = dst + (size_t)idx*8;
#pragma unroll
  for (int jj=0;jj<8;jj++){
    int k = k0 + jj;
    float v = (k < 256) ? Wih[grow*256 + k] : Whh[grow*256 + (k - 256)];
    d[jj] = (half_t)v;
  }
}

// x -> [t][g 0..15][k8 0..7][b 0..15][8] fp16 ; b_global = g*16+b, k = k8*8+jj
__global__ void prep_x(const float* __restrict__ x, half_t* __restrict__ xblk){
  int idx = blockIdx.x*blockDim.x + threadIdx.x;
  if (idx >= 512*16*8*16) return;
  int b = idx & 15;
  int k8 = (idx >> 4) & 7;
  int g = (idx >> 7) & 15;
  int t = idx >> 11;
  const float* src = x + ((size_t)(g*16+b)*512 + (size_t)t)*64 + k8*8;
  half_t* d = xblk + (size_t)idx*8;
#pragma unroll
  for (int jj=0;jj<8;jj++) d[jj] = (half_t)src[jj];
}

// persistent distributed 2-layer LSTM: 16 groups x 8 WGs; WG owns 32 h x 16 batch
// SINGLE combined stamped poll (h0(q-1) + h1(q-2)) and SINGLE barrier per phase
__global__ __launch_bounds__(THREADS, 1) void lstm_dist(
    const half_t* __restrict__ W0blk, const half_t* __restrict__ W1blk,
    const half_t* __restrict__ xblk,
    u32* __restrict__ h0x, u32* __restrict__ h1x,
    const float* __restrict__ b_ih0, const float* __restrict__ b_hh0,
    const float* __restrict__ b_ih1, const float* __restrict__ b_hh1,
    const float* __restrict__ W_head, const float* __restrict__ b_head,
    float* __restrict__ out)
{
  extern __shared__ __align__(16) char smem[];
  half_t* W1lds = (half_t*)smem;                       // [w][kc 0..11][lane][8]
  half_t* hbuf0 = (half_t*)(smem + W1LDS_BYTES);       // slot0: h0|h1 (8192 halves)
  half_t* hbuf1 = hbuf0 + 8192;                        // slot1

  const int tid = threadIdx.x;
  const int wave = tid >> 6, lane = tid & 63;
  const int lcol = lane & 15, kg = lane >> 4;
  const int bid = blockIdx.x;
  const int g = bid >> 3, j = bid & 7;
  const int jw = j*8 + wave;

  // ---- one-time: stage W1 kc0..11 into LDS (12288 u64, coalesced) ----
  {
    u64* dW = (u64*)W1lds;
    for (int u = tid; u < 12288; u += THREADS){
      int w = u / 1536;
      int rem = u - w*1536;
      int kc = rem >> 7;
      int rem2 = rem & 127;
      int ln = rem2 >> 1, hp = rem2 & 1;
      const u64* sp = (const u64*)(W1blk + ((size_t)((j*8+w)*16 + kc)*64 + ln)*8) + hp;
      dW[u] = *sp;
    }
  }

  // ---- one-time: L0 frags + L1 kc12..15 + biases into registers ----
  half8 a0[10], a1r[4];
#pragma unroll
  for (int kc = 0; kc < 10; ++kc)
    a0[kc] = *(const half8*)(W0blk + ((size_t)(jw*10 + kc)*64 + lane)*8);
#pragma unroll
  for (int kc = 0; kc < 4; ++kc)
    a1r[kc] = *(const half8*)(W1blk + ((size_t)(jw*16 + 12 + kc)*64 + lane)*8);
#pragma unroll
  for (int kc = 0; kc < 10; ++kc) asm volatile("" : "+v"(a0[kc]));
#pragma unroll
  for (int kc = 0; kc < 4; ++kc) asm volatile("" : "+v"(a1r[kc]));

  const int hh = jw*4 + kg;                              // lane's hidden index (0..255)
  const int eoff = ((hh>>3)*16 + lcol)*8 + (hh&7);       // exchange element index
  f32x4 bias0, bias1;
#pragma unroll
  for (int ri = 0; ri < 4; ++ri){
    bias0[ri] = b_ih0[ri*256+hh] + b_hh0[ri*256+hh];
    bias1[ri] = b_ih1[ri*256+hh] + b_hh1[ri*256+hh];
  }

  // zero both h staging slots (h0(-1)=h1(-1)=0)
  for (int i = tid; i < 8192; i += THREADS) ((u32*)hbuf0)[i] = 0u;

  float c0 = 0.f, c1 = 0.f;
  half8 xf0, xf1;
  {
    const half_t* xs = xblk + (size_t)g*1024;
    xf0 = *(const half8*)(xs + ((0*4+kg)*16 + lcol)*8);
    xf1 = *(const half8*)(xs + ((1*4+kg)*16 + lcol)*8);
  }
  __syncthreads();   // W1lds + zeroed hbuf visible

  const half_t* w1w = W1lds + (size_t)wave*12*64*8;   // this wave's LDS frag block

  for (int q = 0; q <= TSTEPS; ++q){
    const int sslot = (q+1)&1, dslot = q&1;
    half_t* sb = sslot ? hbuf1 : hbuf0;

    // ---- A) single combined poll+stage: h0(q-1) AND h1(q-2), one pass ----
    if (q > 0){
      const u32 w0want = (u32)q;
      const u32 w1want = (q >= 2) ? (u32)q : 0u;   // h1(-1): memset zeros, stamp 0
      const u64* s0 = (const u64*)(h0x + (size_t)(sslot*GROUPS + g)*4096);
      const u64* s1 = (const u64*)(h1x + (size_t)(sslot*GROUPS + g)*4096);
      u64 v0[4], v1[4];
      int ok = 0;
      for (int tries = 0; !ok && tries < (1<<20); ++tries){
        ok = 1;
#pragma unroll
        for (int i = 0; i < 4; ++i){
          v0[i] = __hip_atomic_load(s0 + tid + i*512, __ATOMIC_RELAXED, __HIP_MEMORY_SCOPE_AGENT);
          v1[i] = __hip_atomic_load(s1 + tid + i*512, __ATOMIC_RELAXED, __HIP_MEMORY_SCOPE_AGENT);
        }
#pragma unroll
        for (int i = 0; i < 4; ++i){
          ok &= (int)((((u32)(v0[i] >> 16) & 0xFFFFu) >= w0want) & (((u32)(v0[i] >> 48)) >= w0want));
          ok &= (int)((((u32)(v1[i] >> 16) & 0xFFFFu) >= w1want) & (((u32)(v1[i] >> 48)) >= w1want));
        }
      }
      u32* lds0 = (u32*)sb;
      u32* lds1 = (u32*)(sb + 4096);
#pragma unroll
      for (int i = 0; i < 4; ++i){
        lds0[tid + i*512] = ((u32)v0[i] & 0xFFFFu) | (((u32)(v0[i] >> 32) & 0xFFFFu) << 16);
        lds1[tid + i*512] = ((u32)v1[i] & 0xFFFFu) | (((u32)(v1[i] >> 32) & 0xFFFFu) << 16);
      }
    }
    __syncthreads();   // staged data visible; single barrier per phase

    const half_t* cb = sb;
    half8 h0f[8];
#pragma unroll
    for (int c = 0; c < 8; ++c)
      h0f[c] = *(const half8*)(cb + ((c*4+kg)*16 + lcol)*8);

    // ---- B) L0: step q ----
    if (q < TSTEPS){
      f32x4 acc = bias0;
      acc = __builtin_amdgcn_mfma_f32_16x16x32_f16(a0[0], xf0, acc, 0,0,0);
      acc = __builtin_amdgcn_mfma_f32_16x16x32_f16(a0[1], xf1, acc, 0,0,0);
#pragma unroll
      for (int c = 0; c < 8; ++c)
        acc = __builtin_amdgcn_mfma_f32_16x16x32_f16(a0[c+2], h0f[c], acc, 0,0,0);
      float ig=sigm(acc[0]), fg=sigm(acc[1]), gg=tanh_fast(acc[2]), og=sigm(acc[3]);
      c0 = fg*c0 + ig*gg;
      float hv = og*tanh_fast(c0);
      u32 sv = ((u32)(q+1) << 16) | (u32)__builtin_bit_cast(unsigned short, (half_t)hv);
      __hip_atomic_store(h0x + (size_t)(dslot*GROUPS + g)*4096 + eoff, sv,
                         __ATOMIC_RELAXED, __HIP_MEMORY_SCOPE_AGENT);
    }

    // ---- C) L1: step q-1 (weights kc0..11 from LDS, kc12..15 from regs) ----
    if (q >= 1){
      f32x4 acc = bias1;
#pragma unroll
      for (int c = 0; c < 8; ++c){
        half8 af = *(const half8*)(w1w + ((size_t)c*64 + lane)*8);
        acc = __builtin_amdgcn_mfma_f32_16x16x32_f16(af, h0f[c], acc, 0,0,0);
      }
#pragma unroll
      for (int c = 0; c < 4; ++c){
        half8 af = *(const half8*)(w1w + ((size_t)(8+c)*64 + lane)*8);
        half8 h1f = *(const half8*)(cb + 4096 + ((c*4+kg)*16 + lcol)*8);
        acc = __builtin_amdgcn_mfma_f32_16x16x32_f16(af, h1f, acc, 0,0,0);
      }
#pragma unroll
      for (int c = 4; c < 8; ++c){
        half8 h1f = *(const half8*)(cb + 4096 + ((c*4+kg)*16 + lcol)*8);
        acc = __builtin_amdgcn_mfma_f32_16x16x32_f16(a1r[c-4], h1f, acc, 0,0,0);
      }
      float ig=sigm(acc[0]), fg=sigm(acc[1]), gg=tanh_fast(acc[2]), og=sigm(acc[3]);
      c1 = fg*c1 + ig*gg;
      float hv = og*tanh_fast(c1);
      u32 sv = ((u32)(q+1) << 16) | (u32)__builtin_bit_cast(unsigned short, (half_t)hv);
      __hip_atomic_store(h1x + (size_t)(dslot*GROUPS + g)*4096 + eoff, sv,
                         __ATOMIC_RELAXED, __HIP_MEMORY_SCOPE_AGENT);
    }

    // ---- D) x prefetch (overlaps next phase's poll) ----
    if (q+1 < TSTEPS){
      const half_t* xs = xblk + (size_t)((q+1)*16 + g)*1024;
      xf0 = *(const half8*)(xs + ((0*4+kg)*16 + lcol)*8);
      xf1 = *(const half8*)(xs + ((1*4+kg)*16 + lcol)*8);
    }
  }

  __syncthreads();

  // ---- head: poll final h1(511) (slot 0, stamp 513), stage, GEMV ----
  {
    const u64* s1 = (const u64*)(h1x + (size_t)(0*GROUPS + g)*4096);
    const u32 want = (u32)(TSTEPS + 1);
    u64 v[4];
    int ok = 0;
    for (int tries = 0; !ok && tries < (1<<20); ++tries){
      ok = 1;
#pragma unroll
      for (int i = 0; i < 4; ++i)
        v[i] = __hip_atomic_load(s1 + tid + i*512, __ATOMIC_RELAXED, __HIP_MEMORY_SCOPE_AGENT);
#pragma unroll
      for (int i = 0; i < 4; ++i)
        ok &= (int)((((u32)(v[i] >> 16) & 0xFFFFu) >= want) & (((u32)(v[i] >> 48)) >= want));
    }
    u32* hd = (u32*)hbuf0;
#pragma unroll
    for (int i = 0; i < 4; ++i)
      hd[tid + i*512] = ((u32)v[i] & 0xFFFFu) | (((u32)(v[i] >> 32) & 0xFFFFu) << 16);
    __syncthreads();

    if (tid < 240){
      int bl = 2*j + (tid >= 120 ? 1 : 0);
      int o = tid % 120;
      float s2 = b_head[o];
      const float* wr = W_head + (size_t)o*256;
#pragma unroll 4
      for (int k8 = 0; k8 < 32; ++k8){
        half8 hv = *(const half8*)(hbuf0 + (k8*16 + bl)*8);
#pragma unroll
        for (int jj = 0; jj < 8; ++jj)
          s2 += (float)hv[jj] * wr[k8*8 + jj];
      }
      out[((size_t)(g*16 + bl))*120 + o] = s2;
    }
  }
}

extern "C" void kernel_launch(void* const* d_in, const int* in_sizes, int n_in,
                              void* d_out, int out_size, void* d_ws, size_t ws_size,
                              hipStream_t stream){
  const float* x     = (const float*)d_in[0];
  const float* W_ih0 = (const float*)d_in[1];
  const float* W_hh0 = (const float*)d_in[2];
  const float* b_ih0 = (const float*)d_in[3];
  const float* b_hh0 = (const float*)d_in[4];
  const float* W_ih1 = (const float*)d_in[5];
  const float* W_hh1 = (const float*)d_in[6];
  const float* b_ih1 = (const float*)d_in[7];
  const float* b_hh1 = (const float*)d_in[8];
  const float* W_head= (const float*)d_in[9];
  const float* b_head= (const float*)d_in[10];
  float* out = (float*)d_out;

  half_t* W0blk = (half_t*)d_ws;
  half_t* W1blk = W0blk + W0_HALVES;
  half_t* xblk  = W1blk + W1_HALVES;
  u32*    h0x   = (u32*)(xblk + X_HALVES);
  u32*    h1x   = h0x + HX_U32;

  // zero stamped exchange buffers every launch (graph-replay safe)
  (void)hipMemsetAsync(h0x, 0, (size_t)HX_U32*2*4, stream);   // h0x + h1x contiguous

  hipLaunchKernelGGL(prep_w0, dim3(160), dim3(256), 0, stream, W_ih0, W_hh0, W0blk);
  hipLaunchKernelGGL(prep_w1, dim3(256), dim3(256), 0, stream, W_ih1, W_hh1, W1blk);
  hipLaunchKernelGGL(prep_x,  dim3(4096), dim3(256), 0, stream, x, xblk);

  (void)hipFuncSetAttribute((const void*)lstm_dist,
                            hipFuncAttributeMaxDynamicSharedMemorySize, LDS_TOTAL);

  hipLaunchKernelGGL(lstm_dist, dim3(NWG), dim3(THREADS), LDS_TOTAL, stream,
                     W0blk, W1blk, xblk, h0x, h1x,
                     b_ih0, b_hh0, b_ih1, b_hh1, W_head, b_head, out);
}

// Round 14
// 1523.561 us; speedup vs baseline: 1.0431x; 1.0431x over previous
//
#include <hip/hip_runtime.h>

typedef _Float16 half_t;
typedef _Float16 half8 __attribute__((ext_vector_type(8)));
typedef float f32x4 __attribute__((ext_vector_type(4)));
typedef unsigned long long u64;
typedef unsigned int u32;

#define GROUPS 16
#define WPG 8
#define NWG 128
#define THREADS 512
#define TSTEPS 512

// ws layout
#define W0_HALVES (8*8*10*64*8)    // 327680 halves
#define W1_HALVES (8*8*16*64*8)    // 524288 halves
#define X_HALVES  (512*16*1024)    // 8388608 halves
#define HX_U32    (2*GROUPS*4096)  // per layer: 2 slots x 16 groups x 4096 stamped u32

__device__ __forceinline__ float sigm(float x){ return 1.f/(1.f+__expf(-x)); }
__device__ __forceinline__ float tanh_fast(float x){ float e=__expf(2.f*x); return 1.f - 2.f/(e+1.f); }

// W0 blocks: [jw 0..63][kc 0..9][lane][8]; wave jw owns h [jw*4, jw*4+4)
// tile row tr=lane&15: gate=tr&3, h_local=tr>>2 ; grow = gate*256 + jw*4 + h_local
// k = kc*32 + (lane>>4)*8 + jj ; K = [x(64) | h0(256)]
__global__ void prep_w0(const float* __restrict__ Wih, const float* __restrict__ Whh,
                        half_t* __restrict__ dst){
  int idx = blockIdx.x*blockDim.x + threadIdx.x;
  if (idx >= 8*8*10*64) return;
  int lane = idx & 63;
  int kc = (idx >> 6) % 10;
  int jw = idx / 640;
  int tr = lane & 15, kg = lane >> 4;
  int grow = (tr&3)*256 + jw*4 + (tr>>2);
  int k0 = kc*32 + kg*8;
  half_t* d = dst + (size_t)idx*8;
#pragma unroll
  for (int jj=0;jj<8;jj++){
    int k = k0 + jj;
    float v = (k < 64) ? Wih[grow*64 + k] : Whh[grow*256 + (k - 64)];
    d[jj] = (half_t)v;
  }
}

// W1 blocks: [jw][kc 0..15][lane][8]; K = [h0(256) | h1(256)]
__global__ void prep_w1(const float* __restrict__ Wih, const float* __restrict__ Whh,
                        half_t* __restrict__ dst){
  int idx = blockIdx.x*blockDim.x + threadIdx.x;
  if (idx >= 8*8*16*64) return;
  int lane = idx & 63;
  int kc = (idx >> 6) & 15;
  int jw = idx >> 10;
  int tr = lane & 15, kg = lane >> 4;
  int grow = (tr&3)*256 + jw*4 + (tr>>2);
  int k0 = kc*32 + kg*8;
  half_t* d = dst + (size_t)idx*8;
#pragma unroll
  for (int jj=0;jj<8;jj++){
    int k = k0 + jj;
    float v = (k < 256) ? Wih[grow*256 + k] : Whh[grow*256 + (k - 256)];
    d[jj] = (half_t)v;
  }
}

// x -> [t][g 0..15][k8 0..7][b 0..15][8] fp16 ; b_global = g*16+b, k = k8*8+jj
__global__ void prep_x(const float* __restrict__ x, half_t* __restrict__ xblk){
  int idx = blockIdx.x*blockDim.x + threadIdx.x;
  if (idx >= 512*16*8*16) return;
  int b = idx & 15;
  int k8 = (idx >> 4) & 7;
  int g = (idx >> 7) & 15;
  int t = idx >> 11;
  const float* src = x + ((size_t)(g*16+b)*512 + (size_t)t)*64 + k8*8;
  half_t* d = xblk + (size_t)idx*8;
#pragma unroll
  for (int jj=0;jj<8;jj++) d[jj] = (half_t)src[jj];
}

// persistent distributed 2-layer LSTM: 16 groups x 8 WGs; WG owns 32 h x 16 batch
// exchange: per-value stamped u32 ((step+1)<<16 | fp16) -> poll IS the data, 1 RTT
// setprio(1) around compute+store so producer stores issue ASAP (consumer-observed
// latency is the critical path); setprio(0) during polls.
__global__ __launch_bounds__(THREADS, 1) void lstm_dist(
    const half_t* __restrict__ W0blk, const half_t* __restrict__ W1blk,
    const half_t* __restrict__ xblk,
    u32* __restrict__ h0x, u32* __restrict__ h1x,
    const float* __restrict__ b_ih0, const float* __restrict__ b_hh0,
    const float* __restrict__ b_ih1, const float* __restrict__ b_hh1,
    const float* __restrict__ W_head, const float* __restrict__ b_head,
    float* __restrict__ out)
{
  __shared__ __align__(16) half_t hbuf[2][8192];  // [slot][h0:4096 | h1:4096] halves

  const int tid = threadIdx.x;
  const int wave = tid >> 6, lane = tid & 63;
  const int lcol = lane & 15, kg = lane >> 4;
  const int bid = blockIdx.x;
  const int g = bid >> 3, j = bid & 7;
  const int jw = j*8 + wave;

  // ---- one-time: A-fragments + biases into registers ----
  half8 a0[10], a1[16];
#pragma unroll
  for (int kc = 0; kc < 10; ++kc)
    a0[kc] = *(const half8*)(W0blk + ((size_t)(jw*10 + kc)*64 + lane)*8);
#pragma unroll
  for (int kc = 0; kc < 16; ++kc)
    a1[kc] = *(const half8*)(W1blk + ((size_t)(jw*16 + kc)*64 + lane)*8);
#pragma unroll
  for (int kc = 0; kc < 10; ++kc) asm volatile("" : "+v"(a0[kc]));
#pragma unroll
  for (int kc = 0; kc < 16; ++kc) asm volatile("" : "+v"(a1[kc]));

  const int hh = jw*4 + kg;                              // lane's hidden index (0..255)
  const int eoff = ((hh>>3)*16 + lcol)*8 + (hh&7);       // exchange/LDS element index
  f32x4 bias0, bias1;
#pragma unroll
  for (int ri = 0; ri < 4; ++ri){
    bias0[ri] = b_ih0[ri*256+hh] + b_hh0[ri*256+hh];
    bias1[ri] = b_ih1[ri*256+hh] + b_hh1[ri*256+hh];
  }

  // zero both LDS slots (serves as h0(-1)=h1(-1)=h1(-2)=0)
  for (int i = tid; i < 8192; i += THREADS) ((u32*)hbuf)[i] = 0u;

  float c0 = 0.f, c1 = 0.f;
  half8 xf0, xf1;
  {
    const half_t* xs = xblk + (size_t)g*1024;
    xf0 = *(const half8*)(xs + ((0*4+kg)*16 + lcol)*8);
    xf1 = *(const half8*)(xs + ((1*4+kg)*16 + lcol)*8);
  }
  __syncthreads();

  for (int q = 0; q <= TSTEPS; ++q){
    const int sslot = (q+1)&1, dslot = q&1;
    const u32 want = (u32)q;

    // ---- A) poll+stage h0(q-1): stamped payload poll (poll IS the fetch) ----
    if (q > 0){
      const u64* s0 = (const u64*)(h0x + (size_t)(sslot*GROUPS + g)*4096);
      u64 v[4];
      int ok = 0;
      for (int tries = 0; !ok && tries < (1<<20); ++tries){
        ok = 1;
#pragma unroll
        for (int i = 0; i < 4; ++i)
          v[i] = __hip_atomic_load(s0 + tid + i*512, __ATOMIC_RELAXED, __HIP_MEMORY_SCOPE_AGENT);
#pragma unroll
        for (int i = 0; i < 4; ++i)
          ok &= (int)((((u32)(v[i] >> 16) & 0xFFFFu) >= want) & (((u32)(v[i] >> 48)) >= want));
      }
      u32* lds0 = (u32*)hbuf[sslot];
#pragma unroll
      for (int i = 0; i < 4; ++i)
        lds0[tid + i*512] = ((u32)v[i] & 0xFFFFu) | (((u32)(v[i] >> 32) & 0xFFFFu) << 16);
    }
    __syncthreads();   // also drains (vmcnt 0) last phase's L1 stores -> slot-reuse safe

    const half_t* cb = hbuf[sslot];
    half8 h0f[8];
#pragma unroll
    for (int c = 0; c < 8; ++c)
      h0f[c] = *(const half8*)(cb + ((c*4+kg)*16 + lcol)*8);

    // ---- B) L0: step q (high prio: get the h0 store out ASAP) ----
    if (q < TSTEPS){
      __builtin_amdgcn_s_setprio(1);
      f32x4 acc = bias0;
      acc = __builtin_amdgcn_mfma_f32_16x16x32_f16(a0[0], xf0, acc, 0,0,0);
      acc = __builtin_amdgcn_mfma_f32_16x16x32_f16(a0[1], xf1, acc, 0,0,0);
#pragma unroll
      for (int c = 0; c < 8; ++c)
        acc = __builtin_amdgcn_mfma_f32_16x16x32_f16(a0[c+2], h0f[c], acc, 0,0,0);
      float ig=sigm(acc[0]), fg=sigm(acc[1]), gg=tanh_fast(acc[2]), og=sigm(acc[3]);
      c0 = fg*c0 + ig*gg;
      float hv = og*tanh_fast(c0);
      u32 sv = ((u32)(q+1) << 16) | (u32)__builtin_bit_cast(unsigned short, (half_t)hv);
      __hip_atomic_store(h0x + (size_t)(dslot*GROUPS + g)*4096 + eoff, sv,
                         __ATOMIC_RELAXED, __HIP_MEMORY_SCOPE_AGENT);
      __builtin_amdgcn_s_setprio(0);
      __builtin_amdgcn_sched_barrier(0);   // issue the store before the h1 poll
    }

    // ---- C) poll+stage h1(q-2): overlaps producers' L1 of phase q-1 ----
    if (q > 1){
      const u64* s1 = (const u64*)(h1x + (size_t)(sslot*GROUPS + g)*4096);
      u64 v[4];
      int ok = 0;
      for (int tries = 0; !ok && tries < (1<<20); ++tries){
        ok = 1;
#pragma unroll
        for (int i = 0; i < 4; ++i)
          v[i] = __hip_atomic_load(s1 + tid + i*512, __ATOMIC_RELAXED, __HIP_MEMORY_SCOPE_AGENT);
#pragma unroll
        for (int i = 0; i < 4; ++i)
          ok &= (int)((((u32)(v[i] >> 16) & 0xFFFFu) >= want) & (((u32)(v[i] >> 48)) >= want));
      }
      u32* lds1 = (u32*)(hbuf[sslot] + 4096);
#pragma unroll
      for (int i = 0; i < 4; ++i)
        lds1[tid + i*512] = ((u32)v[i] & 0xFFFFu) | (((u32)(v[i] >> 32) & 0xFFFFu) << 16);
    }
    __syncthreads();   // drains this phase's L0 store too (overlapped with the poll)

    // ---- D) L1: step q-1 (high prio) ----
    if (q >= 1){
      __builtin_amdgcn_s_setprio(1);
      f32x4 acc = bias1;
#pragma unroll
      for (int c = 0; c < 8; ++c)
        acc = __builtin_amdgcn_mfma_f32_16x16x32_f16(a1[c], h0f[c], acc, 0,0,0);
#pragma unroll
      for (int c = 0; c < 8; ++c){
        half8 h1f = *(const half8*)(cb + 4096 + ((c*4+kg)*16 + lcol)*8);
        acc = __builtin_amdgcn_mfma_f32_16x16x32_f16(a1[c+8], h1f, acc, 0,0,0);
      }
      float ig=sigm(acc[0]), fg=sigm(acc[1]), gg=tanh_fast(acc[2]), og=sigm(acc[3]);
      c1 = fg*c1 + ig*gg;
      float hv = og*tanh_fast(c1);
      u32 sv = ((u32)(q+1) << 16) | (u32)__builtin_bit_cast(unsigned short, (half_t)hv);
      __hip_atomic_store(h1x + (size_t)(dslot*GROUPS + g)*4096 + eoff, sv,
                         __ATOMIC_RELAXED, __HIP_MEMORY_SCOPE_AGENT);
      __builtin_amdgcn_s_setprio(0);
    }

    // ---- E) x prefetch for next phase (overlaps next poll) ----
    if (q+1 < TSTEPS){
      const half_t* xs = xblk + (size_t)((q+1)*16 + g)*1024;
      xf0 = *(const half8*)(xs + ((0*4+kg)*16 + lcol)*8);
      xf1 = *(const half8*)(xs + ((1*4+kg)*16 + lcol)*8);
    }
  }

  __syncthreads();

  // ---- head: poll final h1(511) (slot 0, stamp 513), stage, GEMV ----
  {
    const u64* s1 = (const u64*)(h1x + (size_t)(0*GROUPS + g)*4096);
    const u32 want = (u32)(TSTEPS + 1);
    u64 v[4];
    int ok = 0;
    for (int tries = 0; !ok && tries < (1<<20); ++tries){
      ok = 1;
#pragma unroll
      for (int i = 0; i < 4; ++i)
        v[i] = __hip_atomic_load(s1 + tid + i*512, __ATOMIC_RELAXED, __HIP_MEMORY_SCOPE_AGENT);
#pragma unroll
      for (int i = 0; i < 4; ++i)
        ok &= (int)((((u32)(v[i] >> 16) & 0xFFFFu) >= want) & (((u32)(v[i] >> 48)) >= want));
    }
    u32* hd = (u32*)hbuf[0];
#pragma unroll
    for (int i = 0; i < 4; ++i)
      hd[tid + i*512] = ((u32)v[i] & 0xFFFFu) | (((u32)(v[i] >> 32) & 0xFFFFu) << 16);
    __syncthreads();

    if (tid < 240){
      int bl = 2*j + (tid >= 120 ? 1 : 0);
      int o = tid % 120;
      float s2 = b_head[o];
      const float* wr = W_head + (size_t)o*256;
#pragma unroll 4
      for (int k8 = 0; k8 < 32; ++k8){
        half8 hv = *(const half8*)(hbuf[0] + (k8*16 + bl)*8);
#pragma unroll
        for (int jj = 0; jj < 8; ++jj)
          s2 += (float)hv[jj] * wr[k8*8 + jj];
      }
      out[((size_t)(g*16 + bl))*120 + o] = s2;
    }
  }
}

extern "C" void kernel_launch(void* const* d_in, const int* in_sizes, int n_in,
                              void* d_out, int out_size, void* d_ws, size_t ws_size,
                              hipStream_t stream){
  const float* x     = (const float*)d_in[0];
  const float* W_ih0 = (const float*)d_in[1];
  const float* W_hh0 = (const float*)d_in[2];
  const float* b_ih0 = (const float*)d_in[3];
  const float* b_hh0 = (const float*)d_in[4];
  const float* W_ih1 = (const float*)d_in[5];
  const float* W_hh1 = (const float*)d_in[6];
  const float* b_ih1 = (const float*)d_in[7];
  const float* b_hh1 = (const float*)d_in[8];
  const float* W_head= (const float*)d_in[9];
  const float* b_head= (const float*)d_in[10];
  float* out = (float*)d_out;

  half_t* W0blk = (half_t*)d_ws;
  half_t* W1blk = W0blk + W0_HALVES;
  half_t* xblk  = W1blk + W1_HALVES;
  u32*    h0x   = (u32*)(xblk + X_HALVES);
  u32*    h1x   = h0x + HX_U32;

  // zero stamped exchange buffers every launch (graph-replay safe)
  (void)hipMemsetAsync(h0x, 0, (size_t)HX_U32*2*4, stream);   // h0x + h1x contiguous

  hipLaunchKernelGGL(prep_w0, dim3(160), dim3(256), 0, stream, W_ih0, W_hh0, W0blk);
  hipLaunchKernelGGL(prep_w1, dim3(256), dim3(256), 0, stream, W_ih1, W_hh1, W1blk);
  hipLaunchKernelGGL(prep_x,  dim3(4096), dim3(256), 0, stream, x, xblk);

  hipLaunchKernelGGL(lstm_dist, dim3(NWG), dim3(THREADS), 0, stream,
                     W0blk, W1blk, xblk, h0x, h1x,
                     b_ih0, b_hh0, b_ih1, b_hh1, W_head, b_head, out);
}

// Round 15
// 1421.396 us; speedup vs baseline: 1.1181x; 1.0719x over previous
//
#include <hip/hip_runtime.h>

typedef _Float16 half_t;
typedef _Float16 half8 __attribute__((ext_vector_type(8)));
typedef float f32x4 __attribute__((ext_vector_type(4)));
typedef unsigned long long u64;
typedef unsigned int u32;
typedef unsigned short u16;

#define GROUPS 16
#define WPG 8
#define NWG 128
#define THREADS 512
#define TSTEPS 512

// ws layout
#define W0_HALVES (8*8*10*64*8)    // 327680 halves
#define W1_HALVES (8*8*16*64*8)    // 524288 halves
#define X_HALVES  (512*16*1024)    // 8388608 halves
#define HX_U32    (2*GROUPS*4096)  // per layer: 2 slots x 16 groups x 4096 stamped u32

__device__ __forceinline__ float sigm(float x){ return 1.f/(1.f+__expf(-x)); }
__device__ __forceinline__ float tanh_fast(float x){ float e=__expf(2.f*x); return 1.f - 2.f/(e+1.f); }

// W0 blocks: [jw 0..63][kc 0..9][lane][8]; wave jw owns h [jw*4, jw*4+4)
__global__ void prep_w0(const float* __restrict__ Wih, const float* __restrict__ Whh,
                        half_t* __restrict__ dst){
  int idx = blockIdx.x*blockDim.x + threadIdx.x;
  if (idx >= 8*8*10*64) return;
  int lane = idx & 63;
  int kc = (idx >> 6) % 10;
  int jw = idx / 640;
  int tr = lane & 15, kg = lane >> 4;
  int grow = (tr&3)*256 + jw*4 + (tr>>2);
  int k0 = kc*32 + kg*8;
  half_t* d = dst + (size_t)idx*8;
#pragma unroll
  for (int jj=0;jj<8;jj++){
    int k = k0 + jj;
    float v = (k < 64) ? Wih[grow*64 + k] : Whh[grow*256 + (k - 64)];
    d[jj] = (half_t)v;
  }
}

// W1 blocks: [jw][kc 0..15][lane][8]; K = [h0(256) | h1(256)]
__global__ void prep_w1(const float* __restrict__ Wih, const float* __restrict__ Whh,
                        half_t* __restrict__ dst){
  int idx = blockIdx.x*blockDim.x + threadIdx.x;
  if (idx >= 8*8*16*64) return;
  int lane = idx & 63;
  int kc = (idx >> 6) & 15;
  int jw = idx >> 10;
  int tr = lane & 15, kg = lane >> 4;
  int grow = (tr&3)*256 + jw*4 + (tr>>2);
  int k0 = kc*32 + kg*8;
  half_t* d = dst + (size_t)idx*8;
#pragma unroll
  for (int jj=0;jj<8;jj++){
    int k = k0 + jj;
    float v = (k < 256) ? Wih[grow*256 + k] : Whh[grow*256 + (k - 256)];
    d[jj] = (half_t)v;
  }
}

// x -> [t][g 0..15][k8 0..7][b 0..15][8] fp16
__global__ void prep_x(const float* __restrict__ x, half_t* __restrict__ xblk){
  int idx = blockIdx.x*blockDim.x + threadIdx.x;
  if (idx >= 512*16*8*16) return;
  int b = idx & 15;
  int k8 = (idx >> 4) & 7;
  int g = (idx >> 7) & 15;
  int t = idx >> 11;
  const float* src = x + ((size_t)(g*16+b)*512 + (size_t)t)*64 + k8*8;
  half_t* d = xblk + (size_t)idx*8;
#pragma unroll
  for (int jj=0;jj<8;jj++) d[jj] = (half_t)src[jj];
}

// stamped-poll a 16 KB layer slice (2048 u64 / 512 threads = 4 u64/thread) and
// scatter packed fp16 into LDS fragment layout.
// exchange layout is WAVE-MAJOR: e = jw*64 + lane  -> producer stores fully coalesced.
// decode of u64 index m (covers e=2m,2m+1): jw=m>>5, kg=(m>>3)&3, lcol=(2m)&15.
__device__ __forceinline__ void poll_stage(const u64* s, half_t* sb, int tid, u32 want){
  u64 v[4];
  int ok = 0;
  for (int tries = 0; !ok && tries < (1<<20); ++tries){
    ok = 1;
#pragma unroll
    for (int i = 0; i < 4; ++i)
      v[i] = __hip_atomic_load(s + tid + i*512, __ATOMIC_RELAXED, __HIP_MEMORY_SCOPE_AGENT);
#pragma unroll
    for (int i = 0; i < 4; ++i)
      ok &= (int)((((u32)(v[i] >> 16) & 0xFFFFu) >= want) & (((u32)(v[i] >> 48)) >= want));
  }
#pragma unroll
  for (int i = 0; i < 4; ++i){
    int m = tid + i*512;
    int jw2 = m >> 5, kg2 = (m >> 3) & 3, lc0 = (2*m) & 15;
    int hh2 = jw2*4 + kg2;
    half_t* d = sb + ((hh2 >> 3)*16 + lc0)*8 + (hh2 & 7);
    d[0] = __builtin_bit_cast(half_t, (u16)(v[i] & 0xFFFFu));
    d[8] = __builtin_bit_cast(half_t, (u16)((v[i] >> 32) & 0xFFFFu));
  }
}

// persistent distributed 2-layer LSTM: 16 groups x 8 WGs; WG owns 32 h x 16 batch
// exchange: per-value stamped u32 ((step+1)<<16 | fp16), wave-major coalesced stores
__global__ __launch_bounds__(THREADS, 1) void lstm_dist(
    const half_t* __restrict__ W0blk, const half_t* __restrict__ W1blk,
    const half_t* __restrict__ xblk,
    u32* __restrict__ h0x, u32* __restrict__ h1x,
    const float* __restrict__ b_ih0, const float* __restrict__ b_hh0,
    const float* __restrict__ b_ih1, const float* __restrict__ b_hh1,
    const float* __restrict__ W_head, const float* __restrict__ b_head,
    float* __restrict__ out)
{
  __shared__ __align__(16) half_t hbuf[2][8192];  // [slot][h0:4096 | h1:4096] halves

  const int tid = threadIdx.x;
  const int wave = tid >> 6, lane = tid & 63;
  const int lcol = lane & 15, kg = lane >> 4;
  const int bid = blockIdx.x;
  const int g = bid >> 3, j = bid & 7;
  const int jw = j*8 + wave;

  // ---- one-time: A-fragments + biases into registers ----
  half8 a0[10], a1[16];
#pragma unroll
  for (int kc = 0; kc < 10; ++kc)
    a0[kc] = *(const half8*)(W0blk + ((size_t)(jw*10 + kc)*64 + lane)*8);
#pragma unroll
  for (int kc = 0; kc < 16; ++kc)
    a1[kc] = *(const half8*)(W1blk + ((size_t)(jw*16 + kc)*64 + lane)*8);
#pragma unroll
  for (int kc = 0; kc < 10; ++kc) asm volatile("" : "+v"(a0[kc]));
#pragma unroll
  for (int kc = 0; kc < 16; ++kc) asm volatile("" : "+v"(a1[kc]));

  const int hh = jw*4 + kg;                 // lane's hidden index (0..255)
  const int eoff = jw*64 + lane;            // WAVE-MAJOR exchange u32 index
  f32x4 bias0, bias1;
#pragma unroll
  for (int ri = 0; ri < 4; ++ri){
    bias0[ri] = b_ih0[ri*256+hh] + b_hh0[ri*256+hh];
    bias1[ri] = b_ih1[ri*256+hh] + b_hh1[ri*256+hh];
  }

  // zero both LDS slots (serves as h0(-1)=h1(-1)=h1(-2)=0)
  for (int i = tid; i < 8192; i += THREADS) ((u32*)hbuf)[i] = 0u;

  float c0 = 0.f, c1 = 0.f;
  half8 xf0, xf1;
  {
    const half_t* xs = xblk + (size_t)g*1024;
    xf0 = *(const half8*)(xs + ((0*4+kg)*16 + lcol)*8);
    xf1 = *(const half8*)(xs + ((1*4+kg)*16 + lcol)*8);
  }
  __syncthreads();

  for (int q = 0; q <= TSTEPS; ++q){
    const int sslot = (q+1)&1, dslot = q&1;
    const u32 want = (u32)q;

    // ---- A) poll+stage h0(q-1) (poll IS the fetch; scatter to fragment LDS) ----
    if (q > 0)
      poll_stage((const u64*)(h0x + (size_t)(sslot*GROUPS + g)*4096),
                 hbuf[sslot], tid, want);
    __syncthreads();   // staged h0 visible; drains last phase's L1 stores (slot-reuse safe)

    const half_t* cb = hbuf[sslot];
    half8 h0f[8];
#pragma unroll
    for (int c = 0; c < 8; ++c)
      h0f[c] = *(const half8*)(cb + ((c*4+kg)*16 + lcol)*8);

    // ---- B) L0: step q (high prio: issue the coalesced h0 store ASAP) ----
    if (q < TSTEPS){
      __builtin_amdgcn_s_setprio(1);
      f32x4 acc = bias0;
      acc = __builtin_amdgcn_mfma_f32_16x16x32_f16(a0[0], xf0, acc, 0,0,0);
      acc = __builtin_amdgcn_mfma_f32_16x16x32_f16(a0[1], xf1, acc, 0,0,0);
#pragma unroll
      for (int c = 0; c < 8; ++c)
        acc = __builtin_amdgcn_mfma_f32_16x16x32_f16(a0[c+2], h0f[c], acc, 0,0,0);
      float ig=sigm(acc[0]), fg=sigm(acc[1]), gg=tanh_fast(acc[2]), og=sigm(acc[3]);
      c0 = fg*c0 + ig*gg;
      float hv = og*tanh_fast(c0);
      u32 sv = ((u32)(q+1) << 16) | (u32)__builtin_bit_cast(u16, (half_t)hv);
      __hip_atomic_store(h0x + (size_t)(dslot*GROUPS + g)*4096 + eoff, sv,
                         __ATOMIC_RELAXED, __HIP_MEMORY_SCOPE_AGENT);
      __builtin_amdgcn_s_setprio(0);
      __builtin_amdgcn_sched_barrier(0);   // issue the store before the h1 poll
    }

    // ---- C) poll+stage h1(q-2): overlaps producers' L1 of phase q-1 ----
    if (q > 1)
      poll_stage((const u64*)(h1x + (size_t)(sslot*GROUPS + g)*4096),
                 hbuf[sslot] + 4096, tid, want);
    __syncthreads();   // drains this phase's L0 store too (overlapped with the poll)

    // ---- D) L1: step q-1 (high prio) ----
    if (q >= 1){
      __builtin_amdgcn_s_setprio(1);
      f32x4 acc = bias1;
#pragma unroll
      for (int c = 0; c < 8; ++c)
        acc = __builtin_amdgcn_mfma_f32_16x16x32_f16(a1[c], h0f[c], acc, 0,0,0);
#pragma unroll
      for (int c = 0; c < 8; ++c){
        half8 h1f = *(const half8*)(cb + 4096 + ((c*4+kg)*16 + lcol)*8);
        acc = __builtin_amdgcn_mfma_f32_16x16x32_f16(a1[c+8], h1f, acc, 0,0,0);
      }
      float ig=sigm(acc[0]), fg=sigm(acc[1]), gg=tanh_fast(acc[2]), og=sigm(acc[3]);
      c1 = fg*c1 + ig*gg;
      float hv = og*tanh_fast(c1);
      u32 sv = ((u32)(q+1) << 16) | (u32)__builtin_bit_cast(u16, (half_t)hv);
      __hip_atomic_store(h1x + (size_t)(dslot*GROUPS + g)*4096 + eoff, sv,
                         __ATOMIC_RELAXED, __HIP_MEMORY_SCOPE_AGENT);
      __builtin_amdgcn_s_setprio(0);
    }

    // ---- E) x prefetch for next phase (overlaps next poll) ----
    if (q+1 < TSTEPS){
      const half_t* xs = xblk + (size_t)((q+1)*16 + g)*1024;
      xf0 = *(const half8*)(xs + ((0*4+kg)*16 + lcol)*8);
      xf1 = *(const half8*)(xs + ((1*4+kg)*16 + lcol)*8);
    }
  }

  __syncthreads();

  // ---- head: poll final h1(511) (slot 0, stamp 513), scatter-stage, GEMV ----
  {
    poll_stage((const u64*)(h1x + (size_t)(0*GROUPS + g)*4096),
               hbuf[0], tid, (u32)(TSTEPS + 1));
    __syncthreads();

    if (tid < 240){
      int bl = 2*j + (tid >= 120 ? 1 : 0);
      int o = tid % 120;
      float s2 = b_head[o];
      const float* wr = W_head + (size_t)o*256;
#pragma unroll 4
      for (int k8 = 0; k8 < 32; ++k8){
        half8 hv = *(const half8*)(hbuf[0] + (k8*16 + bl)*8);
#pragma unroll
        for (int jj = 0; jj < 8; ++jj)
          s2 += (float)hv[jj] * wr[k8*8 + jj];
      }
      out[((size_t)(g*16 + bl))*120 + o] = s2;
    }
  }
}

extern "C" void kernel_launch(void* const* d_in, const int* in_sizes, int n_in,
                              void* d_out, int out_size, void* d_ws, size_t ws_size,
                              hipStream_t stream){
  const float* x     = (const float*)d_in[0];
  const float* W_ih0 = (const float*)d_in[1];
  const float* W_hh0 = (const float*)d_in[2];
  const float* b_ih0 = (const float*)d_in[3];
  const float* b_hh0 = (const float*)d_in[4];
  const float* W_ih1 = (const float*)d_in[5];
  const float* W_hh1 = (const float*)d_in[6];
  const float* b_ih1 = (const float*)d_in[7];
  const float* b_hh1 = (const float*)d_in[8];
  const float* W_head= (const float*)d_in[9];
  const float* b_head= (const float*)d_in[10];
  float* out = (float*)d_out;

  half_t* W0blk = (half_t*)d_ws;
  half_t* W1blk = W0blk + W0_HALVES;
  half_t* xblk  = W1blk + W1_HALVES;
  u32*    h0x   = (u32*)(xblk + X_HALVES);
  u32*    h1x   = h0x + HX_U32;

  // zero stamped exchange buffers every launch (graph-replay safe)
  (void)hipMemsetAsync(h0x, 0, (size_t)HX_U32*2*4, stream);   // h0x + h1x contiguous

  hipLaunchKernelGGL(prep_w0, dim3(160), dim3(256), 0, stream, W_ih0, W_hh0, W0blk);
  hipLaunchKernelGGL(prep_w1, dim3(256), dim3(256), 0, stream, W_ih1, W_hh1, W1blk);
  hipLaunchKernelGGL(prep_x,  dim3(4096), dim3(256), 0, stream, x, xblk);

  hipLaunchKernelGGL(lstm_dist, dim3(NWG), dim3(THREADS), 0, stream,
                     W0blk, W1blk, xblk, h0x, h1x,
                     b_ih0, b_hh0, b_ih1, b_hh1, W_head, b_head, out);
}